// Round 8
// baseline (127.893 us; speedup 1.0000x reference)
//
#include <hip/hip_runtime.h>

// Additive (Bahdanau) attention, fp32 in/out.
// B=2, L=512, S=512, H=8, E=32, D=64.
// scores[b,h,l,s] = sum_e tanh(q[b,l,h,e] + k[b,s,h,e]) * v[e]  (+ masks)
// A = softmax_s(scores); out[b,l,h,d] = sum_s A * values[b,s,h,d]
//
// tanh(x) = 1 - 2/(exp2(SC*x)+1), SC = 2*log2(e);
// exp2(SC*(q+k)) = exp2(SC*q)*exp2(SC*k). Inner (l,s,e): fma+rcp+fma.
//
// R8: phase 1 reads ek DIRECTLY from L2, no LDS, no barriers. ws_ek is
// repacked e-major (float4[b][h][e4][s]) so fixed-e4 reads are perfectly
// coalesced across lanes (s = lane + 64i). R6/R7 showed the per-tile
// barrier forced all waves into lockstep LDS-burst/VALU-burst phases
// (both pipes ~36-45% loaded, zero overlap); barrier-free streaming lets
// VMEM and VALU overlap wave-by-wave. Single __syncthreads in the kernel
// (sAb handoff to MFMA phase 3). LDS = 4 KB (sAb only).

#define BB 2
#define LL 512
#define SS 512
#define HH 8
#define EE 32
#define DD 64

// d_ws layout (bytes):
//   [0, 1M)   ws_ek : float4[B][H][e4:8][s:512]   (e-major, coalesced reads)
//   [2M, 4M)  ws_eq : float [B][L][H][E]          (exp2(SC*q))
//   [4M, 5M)  ws_vt : ushort[B][H][D][S]          (V^T bf16)
#define WS_EK_OFF 0
#define WS_EQ_OFF (2u * 1024u * 1024u)
#define WS_VT_OFF (4u * 1024u * 1024u)

typedef __attribute__((ext_vector_type(8))) short bf16x8;
typedef __attribute__((ext_vector_type(4))) float f32x4;
typedef __attribute__((ext_vector_type(4))) unsigned u32x4;

__device__ __forceinline__ unsigned short f2bf(float f) {   // fp32->bf16 RNE
    unsigned u = __float_as_uint(f);
    u += 0x7FFFu + ((u >> 16) & 1u);
    return (unsigned short)(u >> 16);
}
__device__ __forceinline__ float fast_exp2(float x) {
#if __has_builtin(__builtin_amdgcn_exp2f)
    return __builtin_amdgcn_exp2f(x);
#else
    return exp2f(x);
#endif
}
__device__ __forceinline__ float fast_rcp(float x) {
    return __builtin_amdgcn_rcpf(x);
}

#define SCV 2.885390081777927f   // 2*log2(e)

// ---------------- prep kernel: 768 blocks x 256 ----------------
// blocks [0,256):   ws_ek (65536 float4 tasks, e-major layout)
// blocks [256,512): ws_eq (65536 float4 tasks)
// blocks [512,768): ws_vt (65536 tasks, 8 s-values -> one 16B store)
__global__ __launch_bounds__(256) void prep_kernel(
    const float* __restrict__ q, const float* __restrict__ k,
    const float* __restrict__ vals, float* __restrict__ ws)
{
    unsigned gid = blockIdx.x * 256 + threadIdx.x;
    if (gid < 65536u) {
        // i = [b:1][h:3][e4:3][s:9]; val = exp2(SC * k[b][s][h][e4*4..+3])
        unsigned i  = gid;
        unsigned s  = i & 511u;
        unsigned e4 = (i >> 9) & 7u;
        unsigned h  = (i >> 12) & 7u;
        unsigned b  = i >> 15;
        float4 kv = *(const float4*)(k + (((size_t)b * SS + s) * HH + h) * EE + e4 * 4);
        float4 ev = make_float4(fast_exp2(SCV * kv.x), fast_exp2(SCV * kv.y),
                                fast_exp2(SCV * kv.z), fast_exp2(SCV * kv.w));
        ((float4*)(ws + WS_EK_OFF / 4))[i] = ev;   // writes coalesced
    } else if (gid < 131072u) {
        unsigned i = gid - 65536u;   // eq: elementwise, q's linear layout
        float4 qv = ((const float4*)q)[i];
        float4 ev = make_float4(fast_exp2(SCV * qv.x), fast_exp2(SCV * qv.y),
                                fast_exp2(SCV * qv.z), fast_exp2(SCV * qv.w));
        ((float4*)(ws + WS_EQ_OFF / 4))[i] = ev;
    } else {
        // vt: p = [b:1][h:3][d:6][sp8:6]; pack 8 s-values -> one 16B store
        unsigned p   = gid - 131072u;
        unsigned sp8 = p & 63u;
        unsigned d   = (p >> 6) & 63u;
        unsigned h   = (p >> 12) & 7u;
        unsigned b   = p >> 15;
        unsigned s0  = sp8 * 8u;
        const float* vb = vals + (((size_t)b * SS + s0) * HH + h) * DD + d;
        u32x4 pk;
        #pragma unroll
        for (int j = 0; j < 4; j++) {
            float f0 = vb[(size_t)(2 * j) * (HH * DD)];
            float f1 = vb[(size_t)(2 * j + 1) * (HH * DD)];
            pk[j] = (unsigned)f2bf(f0) | ((unsigned)f2bf(f1) << 16);
        }
        u32x4* vt4 = (u32x4*)((char*)ws + WS_VT_OFF);
        vt4[((((size_t)b * HH + h) * DD + d) * SS + s0) / 8] = pk;
    }
}

// ---------------- main kernel: 2048 blocks x 256 ----------------
__global__ __launch_bounds__(256) void addattn_kernel(
    const float* __restrict__ ws_ekf,          // e-major ek (float4 image)
    const float* __restrict__ ws_eqf,          // exp2(SC*q)
    const unsigned short* __restrict__ ws_vt,  // V^T bf16 (B,H,D,S)
    const float* __restrict__ vvec,            // (E)
    const float* __restrict__ mask,            // (L,S)
    const float* __restrict__ klen,            // (B,S)
    float* __restrict__ out)                   // (B,L,H,D)
{
    __shared__ unsigned short sAb[4][SS];      // 4 KB, bf16 probs (swizzled)

    const int tid  = threadIdx.x;
    const int w    = tid >> 6;
    const int lane = tid & 63;
    const int bh   = blockIdx.x >> 7;
    const int lblk = blockIdx.x & 127;
    const int b    = bh >> 3;
    const int h    = bh & 7;
    const int l    = lblk * 4 + w;

    // eq / v2: wave-uniform -> compiler scalarizes (R6 measured VGPR=52)
    float4 eq[EE / 4];
    {
        const float4* qrow =
            (const float4*)(ws_eqf + (((size_t)b * LL + l) * HH + h) * EE);
        #pragma unroll
        for (int e4 = 0; e4 < EE / 4; e4++) eq[e4] = qrow[e4];
    }
    float4 v2[EE / 4];
    {
        const float4* vr = (const float4*)vvec;
        #pragma unroll
        for (int i = 0; i < EE / 4; i++) {
            float4 t = vr[i];
            v2[i] = make_float4(-2.f * t.x, -2.f * t.y, -2.f * t.z, -2.f * t.w);
        }
    }

    // ---- Phase 1: barrier-free score streaming from L2. ----
    // ek block for (b,h): float4[e4:8][s:512]; lane reads s = lane + i*64
    // -> each e4 load is 64 consecutive float4 = 1 KB coalesced.
    float sc[SS / 64];
    const float4* ekp = (const float4*)ws_ekf + (size_t)(b * HH + h) * (8 * SS);
    for (int i = 0; i < SS / 64; i++) {
        int s = lane + i * 64;
        float a0 = 0.f, a1 = 0.f, a2 = 0.f, a3 = 0.f;  // 4 indep chains
        #pragma unroll
        for (int e4 = 0; e4 < EE / 4; e4++) {
            float4 kv = ekp[e4 * SS + s];              // coalesced dwordx4
            float4 ev = eq[e4];
            float4 vv = v2[e4];
            a0 = __builtin_fmaf(vv.x, fast_rcp(__builtin_fmaf(ev.x, kv.x, 1.f)), a0);
            a1 = __builtin_fmaf(vv.y, fast_rcp(__builtin_fmaf(ev.y, kv.y, 1.f)), a1);
            a2 = __builtin_fmaf(vv.z, fast_rcp(__builtin_fmaf(ev.z, kv.z, 1.f)), a2);
            a3 = __builtin_fmaf(vv.w, fast_rcp(__builtin_fmaf(ev.w, kv.w, 1.f)), a3);
        }
        sc[i] = (a0 + a1) + (a2 + a3);
    }

    // ---- Phase 2: masks + per-wave softmax -> sAb (bf16, chunk-swizzled) --
    {
        const float* mrow = mask + (size_t)l * SS;
        const float* kl   = klen + (size_t)b * SS;
        float mx = -1e30f;
        #pragma unroll
        for (int i = 0; i < SS / 64; i++) {
            int s = lane + i * 64;
            sc[i] += mrow[s] + kl[s];
            mx = fmaxf(mx, sc[i]);
        }
        #pragma unroll
        for (int off = 1; off < 64; off <<= 1) mx = fmaxf(mx, __shfl_xor(mx, off, 64));
        float ssum = 0.f;
        #pragma unroll
        for (int i = 0; i < SS / 64; i++) {
            sc[i] = __expf(sc[i] - mx);
            ssum += sc[i];
        }
        #pragma unroll
        for (int off = 1; off < 64; off <<= 1) ssum += __shfl_xor(ssum, off, 64);
        float inv = fast_rcp(ssum);
        const int fsw = (w * 5) & 7;           // row swizzle (R7, conflict fix)
        #pragma unroll
        for (int i = 0; i < SS / 64; i++) {
            int col = lane + i * 64;
            int pos = (((col >> 3) ^ fsw) << 3) | (col & 7);
            sAb[w][pos] = f2bf(sc[i] * inv);
        }
    }
    __syncthreads();   // the kernel's ONLY barrier

    // ---- Phase 3: PV via MFMA; B-frag = 1 bf16x8 load from ws_vt. ----
    const int am  = lane & 15;
    const int qd  = lane >> 4;
    const int dof = w * 16 + am;
    const int fam = (am * 5) & 7;              // A-row swizzle
    const unsigned short* vt =
        ws_vt + (((size_t)b * HH + h) * DD + dof) * SS + qd * 8;
    f32x4 acc = {0.f, 0.f, 0.f, 0.f};
    bf16x8 bcur = *(const bf16x8*)vt;
    for (int c = 0; c < SS / 32; c++) {
        bf16x8 bnxt = bcur;
        if (c < SS / 32 - 1) bnxt = *(const bf16x8*)(vt + (c + 1) * 32);
        bf16x8 af = {0, 0, 0, 0, 0, 0, 0, 0};
        if (am < 4)
            af = *(const bf16x8*)&sAb[am][((c * 4 + qd) ^ fam) << 3];
        acc = __builtin_amdgcn_mfma_f32_16x16x32_bf16(af, bcur, acc, 0, 0, 0);
        bcur = bnxt;
    }
    // C layout: col = lane&15 (d), row = qd*4 + reg; valid rows -> qd==0
    if (qd == 0) {
        float* orow = out + (((size_t)b * LL + lblk * 4) * HH + h) * DD + dof;
        #pragma unroll
        for (int r = 0; r < 4; r++)
            orow[(size_t)r * (HH * DD)] = acc[r];
    }
}

extern "C" void kernel_launch(void* const* d_in, const int* in_sizes, int n_in,
                              void* d_out, int out_size, void* d_ws, size_t ws_size,
                              hipStream_t stream) {
    const float* q    = (const float*)d_in[0];
    const float* k    = (const float*)d_in[1];
    const float* vals = (const float*)d_in[2];
    const float* vvec = (const float*)d_in[3];
    const float* mask = (const float*)d_in[4];
    const float* klen = (const float*)d_in[5];
    float* outp = (float*)d_out;

    float* ws = (float*)d_ws;
    prep_kernel<<<dim3(768), dim3(256), 0, stream>>>(q, k, vals, ws);

    const float* ws_ekf = (const float*)((char*)d_ws + WS_EK_OFF);
    const float* ws_eqf = (const float*)((char*)d_ws + WS_EQ_OFF);
    const unsigned short* ws_vt = (const unsigned short*)((char*)d_ws + WS_VT_OFF);
    addattn_kernel<<<dim3(BB * HH * (LL / 4)), dim3(256), 0, stream>>>(
        ws_ekf, ws_eqf, ws_vt, vvec, mask, klen, outp);
}

// Round 9
// 98.728 us; speedup vs baseline: 1.2954x; 1.2954x over previous
//
#include <hip/hip_runtime.h>

// Additive (Bahdanau) attention, fp32 in/out.
// B=2, L=512, S=512, H=8, E=32, D=64.
// scores[b,h,l,s] = sum_e tanh(q[b,l,h,e] + k[b,s,h,e]) * v[e]  (+ masks)
// A = softmax_s(scores); out[b,l,h,d] = sum_s A * values[b,s,h,d]
//
// tanh(x) = 1 - 2/(exp2(SC*x)+1), SC = 2*log2(e);
// exp2(SC*(q+k)) = exp2(SC*q)*exp2(SC*k). Inner (l,s,e): fma+rcp+fma.
// Prep kernel: ws_ek = exp2(SC*k) e-major; ws_eq = exp2(SC*q); ws_vt = V^T bf16.
//
// R8 lesson: direct-L2 streaming stalled on load latency (VALUBusy 29%) —
// 8 loads then serial wait, nothing to overlap. R9 fixes MLP:
//  - 2 l-rows/wave share each k-load -> 768 cyc compute per 4-load batch
//  - explicit 2-stage pipeline (compute cur half while nxt half in flight)
//  - eq for both rows forced to SGPRs via readfirstlane (R4's VGPR blowup
//    was un-scalarized 2-row eq); load buffers only 32 VGPRs.
// Barrier-free phase 1; single __syncthreads (sAb handoff); LDS = 8 KB.

#define BB 2
#define LL 512
#define SS 512
#define HH 8
#define EE 32
#define DD 64

// d_ws layout (bytes):
//   [0, 1M)   ws_ek : float4[B][H][e4:8][s:512]   (e-major, coalesced reads)
//   [2M, 4M)  ws_eq : float [B][L][H][E]          (exp2(SC*q))
//   [4M, 5M)  ws_vt : ushort[B][H][D][S]          (V^T bf16)
#define WS_EK_OFF 0
#define WS_EQ_OFF (2u * 1024u * 1024u)
#define WS_VT_OFF (4u * 1024u * 1024u)

typedef __attribute__((ext_vector_type(8))) short bf16x8;
typedef __attribute__((ext_vector_type(4))) float f32x4;
typedef __attribute__((ext_vector_type(4))) unsigned u32x4;

__device__ __forceinline__ unsigned short f2bf(float f) {   // fp32->bf16 RNE
    unsigned u = __float_as_uint(f);
    u += 0x7FFFu + ((u >> 16) & 1u);
    return (unsigned short)(u >> 16);
}
__device__ __forceinline__ float fast_exp2(float x) {
#if __has_builtin(__builtin_amdgcn_exp2f)
    return __builtin_amdgcn_exp2f(x);
#else
    return exp2f(x);
#endif
}
__device__ __forceinline__ float fast_rcp(float x) {
    return __builtin_amdgcn_rcpf(x);
}
__device__ __forceinline__ float bcastf(float x) {   // force into SGPR
    return __int_as_float(__builtin_amdgcn_readfirstlane(__float_as_int(x)));
}

#define SCV 2.885390081777927f   // 2*log2(e)

// ---------------- prep kernel: 768 blocks x 256 (unchanged from R8) ------
__global__ __launch_bounds__(256) void prep_kernel(
    const float* __restrict__ q, const float* __restrict__ k,
    const float* __restrict__ vals, float* __restrict__ ws)
{
    unsigned gid = blockIdx.x * 256 + threadIdx.x;
    if (gid < 65536u) {
        // i = [b:1][h:3][e4:3][s:9]; val = exp2(SC * k[b][s][h][e4*4..+3])
        unsigned i  = gid;
        unsigned s  = i & 511u;
        unsigned e4 = (i >> 9) & 7u;
        unsigned h  = (i >> 12) & 7u;
        unsigned b  = i >> 15;
        float4 kv = *(const float4*)(k + (((size_t)b * SS + s) * HH + h) * EE + e4 * 4);
        float4 ev = make_float4(fast_exp2(SCV * kv.x), fast_exp2(SCV * kv.y),
                                fast_exp2(SCV * kv.z), fast_exp2(SCV * kv.w));
        ((float4*)(ws + WS_EK_OFF / 4))[i] = ev;
    } else if (gid < 131072u) {
        unsigned i = gid - 65536u;   // eq: elementwise, q's linear layout
        float4 qv = ((const float4*)q)[i];
        float4 ev = make_float4(fast_exp2(SCV * qv.x), fast_exp2(SCV * qv.y),
                                fast_exp2(SCV * qv.z), fast_exp2(SCV * qv.w));
        ((float4*)(ws + WS_EQ_OFF / 4))[i] = ev;
    } else {
        // vt: p = [b:1][h:3][d:6][sp8:6]; pack 8 s-values -> one 16B store
        unsigned p   = gid - 131072u;
        unsigned sp8 = p & 63u;
        unsigned d   = (p >> 6) & 63u;
        unsigned h   = (p >> 12) & 7u;
        unsigned b   = p >> 15;
        unsigned s0  = sp8 * 8u;
        const float* vb = vals + (((size_t)b * SS + s0) * HH + h) * DD + d;
        u32x4 pk;
        #pragma unroll
        for (int j = 0; j < 4; j++) {
            float f0 = vb[(size_t)(2 * j) * (HH * DD)];
            float f1 = vb[(size_t)(2 * j + 1) * (HH * DD)];
            pk[j] = (unsigned)f2bf(f0) | ((unsigned)f2bf(f1) << 16);
        }
        u32x4* vt4 = (u32x4*)((char*)ws + WS_VT_OFF);
        vt4[((((size_t)b * HH + h) * DD + d) * SS + s0) / 8] = pk;
    }
}

// ---------------- main kernel: 1024 blocks x 256 ----------------
__global__ __launch_bounds__(256) void addattn_kernel(
    const float* __restrict__ ws_ekf,          // e-major ek (float4 image)
    const float* __restrict__ ws_eqf,          // exp2(SC*q)
    const unsigned short* __restrict__ ws_vt,  // V^T bf16 (B,H,D,S)
    const float* __restrict__ vvec,            // (E)
    const float* __restrict__ mask,            // (L,S)
    const float* __restrict__ klen,            // (B,S)
    float* __restrict__ out)                   // (B,L,H,D)
{
    __shared__ unsigned short sAb[8][SS];      // 8 KB, bf16 probs (swizzled)

    const int tid  = threadIdx.x;
    const int w    = tid >> 6;
    const int lane = tid & 63;
    const int bh   = blockIdx.x >> 6;          // 16 (b,h) pairs
    const int lblk = blockIdx.x & 63;          // 64 l-blocks of 8 rows
    const int b    = bh >> 3;
    const int h    = bh & 7;
    const int l0   = lblk * 8;                 // block's first l-row
    const int lw   = l0 + 2 * w;               // this wave's first row

    // eq for the wave's 2 rows -> SGPRs via readfirstlane (wave-uniform).
    // v2 = -2*v left to the compiler's scalarizer (uniform, worked R5-R8).
    float eq0[EE], eq1[EE], v2s[EE];
    {
        const float* q0 = ws_eqf + (((size_t)b * LL + lw) * HH + h) * EE;
        const float* q1 = q0 + HH * EE;        // next l, same (b,h)
        #pragma unroll
        for (int e = 0; e < EE; e += 4) {
            float4 t0 = *(const float4*)(q0 + e);
            float4 t1 = *(const float4*)(q1 + e);
            eq0[e] = bcastf(t0.x); eq0[e+1] = bcastf(t0.y);
            eq0[e+2] = bcastf(t0.z); eq0[e+3] = bcastf(t0.w);
            eq1[e] = bcastf(t1.x); eq1[e+1] = bcastf(t1.y);
            eq1[e+2] = bcastf(t1.z); eq1[e+3] = bcastf(t1.w);
        }
        const float4* vr = (const float4*)vvec;
        #pragma unroll
        for (int e4 = 0; e4 < EE / 4; e4++) {
            float4 t = vr[e4];
            v2s[e4*4]   = -2.f * t.x; v2s[e4*4+1] = -2.f * t.y;
            v2s[e4*4+2] = -2.f * t.z; v2s[e4*4+3] = -2.f * t.w;
        }
    }

    // ---- Phase 1: barrier-free pipelined streaming from L2. ----
    // ek block (b,h): float4[e4:8][s:512]; lane reads s = lane + 64*i.
    // Pipeline: compute a 4-e4 half-block (768 cyc for 2 rows) while the
    // next half-block's 4 loads are in flight.
    float sc[2][SS / 64];
    const float4* ekp = (const float4*)ws_ekf + (size_t)(b * HH + h) * (8 * SS);

    float4 cur[4], nxt[4];
    #pragma unroll
    for (int e4 = 0; e4 < 4; e4++) cur[e4] = ekp[e4 * SS + lane];

    for (int i = 0; i < SS / 64; i++) {
        const int s  = lane + i * 64;
        const int sn = lane + ((i + 1) & 7) * 64;   // wraps at end (harmless)
        float a0[4] = {0.f, 0.f, 0.f, 0.f};
        float a1[4] = {0.f, 0.f, 0.f, 0.f};

        #define COMPC(IDX, comp)                                              \
        {                                                                     \
            float p0 = __builtin_fmaf(eq0[IDX], comp, 1.f);                   \
            float p1 = __builtin_fmaf(eq1[IDX], comp, 1.f);                   \
            a0[(IDX) & 3] = __builtin_fmaf(v2s[IDX], fast_rcp(p0), a0[(IDX) & 3]); \
            a1[(IDX) & 3] = __builtin_fmaf(v2s[IDX], fast_rcp(p1), a1[(IDX) & 3]); \
        }
        #define COMP4(E4, kv)                                                 \
        {                                                                     \
            COMPC(4 * (E4) + 0, kv.x) COMPC(4 * (E4) + 1, kv.y)               \
            COMPC(4 * (E4) + 2, kv.z) COMPC(4 * (E4) + 3, kv.w)               \
        }

        // issue high-half loads, then compute low half from cur
        #pragma unroll
        for (int e4 = 0; e4 < 4; e4++) nxt[e4] = ekp[(e4 + 4) * SS + s];
        #pragma unroll
        for (int e4 = 0; e4 < 4; e4++) { float4 kv = cur[e4]; COMP4(e4, kv) }
        // issue next-i low-half loads, then compute high half from nxt
        #pragma unroll
        for (int e4 = 0; e4 < 4; e4++) cur[e4] = ekp[e4 * SS + sn];
        #pragma unroll
        for (int e4 = 0; e4 < 4; e4++) { float4 kv = nxt[e4]; COMP4(e4 + 4, kv) }

        sc[0][i] = (a0[0] + a0[1]) + (a0[2] + a0[3]);
        sc[1][i] = (a1[0] + a1[1]) + (a1[2] + a1[3]);
        #undef COMP4
        #undef COMPC
    }

    // ---- Phase 2: masks + per-row softmax -> sAb (bf16, chunk-swizzled) --
    {
        const float* kl = klen + (size_t)b * SS;
        float klv[SS / 64];
        #pragma unroll
        for (int i = 0; i < SS / 64; i++) klv[i] = kl[lane + i * 64];

        #pragma unroll
        for (int r = 0; r < 2; r++) {
            const float* mrow = mask + (size_t)(lw + r) * SS;
            float mx = -1e30f;
            #pragma unroll
            for (int i = 0; i < SS / 64; i++) {
                sc[r][i] += mrow[lane + i * 64] + klv[i];
                mx = fmaxf(mx, sc[r][i]);
            }
            #pragma unroll
            for (int off = 1; off < 64; off <<= 1) mx = fmaxf(mx, __shfl_xor(mx, off, 64));
            float ssum = 0.f;
            #pragma unroll
            for (int i = 0; i < SS / 64; i++) {
                sc[r][i] = __expf(sc[r][i] - mx);
                ssum += sc[r][i];
            }
            #pragma unroll
            for (int off = 1; off < 64; off <<= 1) ssum += __shfl_xor(ssum, off, 64);
            float inv = fast_rcp(ssum);
            const int row = 2 * w + r;
            const int fsw = (row * 5) & 7;     // chunk swizzle (R7, verified 0-conflict)
            #pragma unroll
            for (int i = 0; i < SS / 64; i++) {
                int col = lane + i * 64;
                int pos = (((col >> 3) ^ fsw) << 3) | (col & 7);
                sAb[row][pos] = f2bf(sc[r][i] * inv);
            }
        }
    }
    __syncthreads();   // the kernel's only barrier

    // ---- Phase 3: PV via MFMA; B-frag = 1 bf16x8 load from ws_vt. ----
    // A = 8x512 probs (rows 8..15 zero), wave w owns d-chunk w*16..+15.
    const int am  = lane & 15;
    const int qd  = lane >> 4;
    const int dof = w * 16 + am;
    const int fam = (am * 5) & 7;              // A-row swizzle (matches write)
    const unsigned short* vt =
        ws_vt + (((size_t)b * HH + h) * DD + dof) * SS + qd * 8;
    f32x4 acc = {0.f, 0.f, 0.f, 0.f};
    bf16x8 bcur = *(const bf16x8*)vt;
    for (int c = 0; c < SS / 32; c++) {
        bf16x8 bnxt = bcur;
        if (c < SS / 32 - 1) bnxt = *(const bf16x8*)(vt + (c + 1) * 32);
        bf16x8 af = {0, 0, 0, 0, 0, 0, 0, 0};
        if (am < 8)
            af = *(const bf16x8*)&sAb[am][((c * 4 + qd) ^ fam) << 3];
        acc = __builtin_amdgcn_mfma_f32_16x16x32_bf16(af, bcur, acc, 0, 0, 0);
        bcur = bnxt;
    }
    // C layout: col = lane&15 (d), row = qd*4 + reg; valid rows 0..7 -> qd<2
    if (qd < 2) {
        float* orow = out + (((size_t)b * LL + l0 + qd * 4) * HH + h) * DD + dof;
        #pragma unroll
        for (int r = 0; r < 4; r++)
            orow[(size_t)r * (HH * DD)] = acc[r];
    }
}

extern "C" void kernel_launch(void* const* d_in, const int* in_sizes, int n_in,
                              void* d_out, int out_size, void* d_ws, size_t ws_size,
                              hipStream_t stream) {
    const float* q    = (const float*)d_in[0];
    const float* k    = (const float*)d_in[1];
    const float* vals = (const float*)d_in[2];
    const float* vvec = (const float*)d_in[3];
    const float* mask = (const float*)d_in[4];
    const float* klen = (const float*)d_in[5];
    float* outp = (float*)d_out;

    float* ws = (float*)d_ws;
    prep_kernel<<<dim3(768), dim3(256), 0, stream>>>(q, k, vals, ws);

    const float* ws_ekf = (const float*)((char*)d_ws + WS_EK_OFF);
    const float* ws_eqf = (const float*)((char*)d_ws + WS_EQ_OFF);
    const unsigned short* ws_vt = (const unsigned short*)((char*)d_ws + WS_VT_OFF);
    addattn_kernel<<<dim3(BB * HH * (LL / 8)), dim3(256), 0, stream>>>(
        ws_ekf, ws_eqf, ws_vt, vvec, mask, klen, outp);
}

// Round 10
// 93.749 us; speedup vs baseline: 1.3642x; 1.0531x over previous
//
#include <hip/hip_runtime.h>

// Additive (Bahdanau) attention, fp32 in/out.
// B=2, L=512, S=512, H=8, E=32, D=64.
// scores[b,h,l,s] = sum_e tanh(q[b,l,h,e] + k[b,s,h,e]) * v[e]  (+ masks)
// A = softmax_s(scores); out[b,l,h,d] = sum_s A * values[b,s,h,d]
//
// tanh(x) = 1 - 2/(exp2(SC*x)+1), SC = 2*log2(e);
// exp2(SC*(q+k)) = exp2(SC*q)*exp2(SC*k). Inner (l,s,e): fma+rcp+fma.
//
// R10: phase-1 operand made LDS-RESIDENT. R6-R9 all plateaued at main
// ~43-50us because every wave privately re-streamed the 64KB ek slab from
// L2 (268-536MB/launch, latency never covered). ek in bf16 is 32KB per
// (b,h): staged ONCE per block, then phase 1 is pure ds_read_b128 (~96cyc
// VALU per 16B read - latency trivially hidden). Phase-1 global traffic
// 268MB -> 33MB. ws_vtf additionally pre-fragmented into MFMA B-operand
// per-lane images -> phase-3 loads perfectly coalesced.
// Block = 256 thr, 8 l-rows (2/wave). LDS = 32K ek + 8K sAb = 40960 B
// -> 4 blocks/CU. Barriers: 2 total (ek staged, sAb handoff).

#define BB 2
#define LL 512
#define SS 512
#define HH 8
#define EE 32
#define DD 64

// d_ws layout (bytes):
//   [0, 512K)  ws_ekb : uint4[B][H][e8:4][s:512]     bf16 pairs, LDS image
//   [2M, 4M)   ws_eq  : float[B][L][H][E]            exp2(SC*q)
//   [4M, 5M)   ws_vtf : uint4[B][H][dchunk:4][c:16][lane:64]  MFMA B-frags
#define WS_EK_OFF 0
#define WS_EQ_OFF (2u * 1024u * 1024u)
#define WS_VT_OFF (4u * 1024u * 1024u)

typedef __attribute__((ext_vector_type(8))) short bf16x8;
typedef __attribute__((ext_vector_type(4))) float f32x4;
typedef __attribute__((ext_vector_type(4))) unsigned u32x4;

__device__ __forceinline__ unsigned short f2bf(float f) {   // fp32->bf16 RNE
    unsigned u = __float_as_uint(f);
    u += 0x7FFFu + ((u >> 16) & 1u);
    return (unsigned short)(u >> 16);
}
__device__ __forceinline__ float fast_exp2(float x) {
#if __has_builtin(__builtin_amdgcn_exp2f)
    return __builtin_amdgcn_exp2f(x);
#else
    return exp2f(x);
#endif
}
__device__ __forceinline__ float fast_rcp(float x) {
    return __builtin_amdgcn_rcpf(x);
}
__device__ __forceinline__ float bcastf(float x) {   // force wave-uniform/SGPR
    return __int_as_float(__builtin_amdgcn_readfirstlane(__float_as_int(x)));
}

#define SCV 2.885390081777927f   // 2*log2(e)

// ---------------- prep kernel: 640 blocks x 256 ----------------
// gid [0,32768):        ws_ekb  (16B bf16 entries)
// gid [32768,98304):    ws_eq   (float4 tasks)
// gid [98304,163840):   ws_vtf  (16B MFMA B-frag entries)
__global__ __launch_bounds__(256) void prep_kernel(
    const float* __restrict__ q, const float* __restrict__ k,
    const float* __restrict__ vals, float* __restrict__ ws)
{
    unsigned gid = blockIdx.x * 256 + threadIdx.x;
    if (gid < 32768u) {
        // i = [b:1][h:3][e8:2][s:9]; entry = bf16(exp2(SC*k[b][s][h][8e8..+7]))
        unsigned i  = gid;
        unsigned s  = i & 511u;
        unsigned e8 = (i >> 9) & 3u;
        unsigned h  = (i >> 11) & 7u;
        unsigned b  = i >> 14;
        const float* kr = k + (((size_t)b * SS + s) * HH + h) * EE + e8 * 8;
        float4 k0 = *(const float4*)kr;
        float4 k1 = *(const float4*)(kr + 4);
        u32x4 pk;
        pk[0] = (unsigned)f2bf(fast_exp2(SCV * k0.x)) |
                ((unsigned)f2bf(fast_exp2(SCV * k0.y)) << 16);
        pk[1] = (unsigned)f2bf(fast_exp2(SCV * k0.z)) |
                ((unsigned)f2bf(fast_exp2(SCV * k0.w)) << 16);
        pk[2] = (unsigned)f2bf(fast_exp2(SCV * k1.x)) |
                ((unsigned)f2bf(fast_exp2(SCV * k1.y)) << 16);
        pk[3] = (unsigned)f2bf(fast_exp2(SCV * k1.z)) |
                ((unsigned)f2bf(fast_exp2(SCV * k1.w)) << 16);
        ((u32x4*)((char*)ws + WS_EK_OFF))[i] = pk;
    } else if (gid < 98304u) {
        unsigned i = gid - 32768u;   // eq: elementwise, q's linear layout
        float4 qv = ((const float4*)q)[i];
        float4 ev = make_float4(fast_exp2(SCV * qv.x), fast_exp2(SCV * qv.y),
                                fast_exp2(SCV * qv.z), fast_exp2(SCV * qv.w));
        ((float4*)(ws + WS_EQ_OFF / 4))[i] = ev;
    } else {
        // vtf: i = [b:1][h:3][dchunk:2][c:4][lane:6]
        // entry = B-frag for (chunk c, lane): V[s=c*32+qd*8+j][d=dchunk*16+n]
        unsigned i      = gid - 98304u;
        unsigned lane   = i & 63u;
        unsigned c      = (i >> 6) & 15u;
        unsigned dchunk = (i >> 10) & 3u;
        unsigned h      = (i >> 12) & 7u;
        unsigned b      = i >> 15;
        unsigned qd = lane >> 4, n = lane & 15;
        unsigned d  = dchunk * 16 + n;
        unsigned s0 = c * 32 + qd * 8;
        const float* vb = vals + (((size_t)b * SS + s0) * HH + h) * DD + d;
        u32x4 pk;
        #pragma unroll
        for (int j2 = 0; j2 < 4; j2++) {
            float f0 = vb[(size_t)(2 * j2) * (HH * DD)];
            float f1 = vb[(size_t)(2 * j2 + 1) * (HH * DD)];
            pk[j2] = (unsigned)f2bf(f0) | ((unsigned)f2bf(f1) << 16);
        }
        ((u32x4*)((char*)ws + WS_VT_OFF))[i] = pk;
    }
}

// ---------------- main kernel: 1024 blocks x 256 ----------------
__global__ __launch_bounds__(256) void addattn_kernel(
    const u32x4* __restrict__ ws_ekb,   // bf16 ek LDS image per (b,h)
    const float* __restrict__ ws_eqf,   // exp2(SC*q)
    const bf16x8* __restrict__ ws_vtf,  // pre-fragmented V (B-operand image)
    const float* __restrict__ vvec,     // (E)
    const float* __restrict__ mask,     // (L,S)
    const float* __restrict__ klen,     // (B,S)
    float* __restrict__ out)            // (B,L,H,D)
{
    __shared__ u32x4 sek[4 * SS];              // 32 KB: [e8:4][s:512] bf16
    __shared__ unsigned short sAb[8][SS];      // 8 KB; total 40960 -> 4 blk/CU

    const int tid  = threadIdx.x;
    const int w    = tid >> 6;
    const int lane = tid & 63;
    const int bh   = blockIdx.x >> 6;          // 16 (b,h) pairs
    const int lblk = blockIdx.x & 63;          // 64 l-blocks of 8 rows
    const int b    = bh >> 3;
    const int h    = bh & 7;
    const int l0   = lblk * 8;
    const int lw   = l0 + 2 * w;               // wave's first row

    // ---- stage ek (32 KB, pure coalesced copy, 8 x 16B per thread) ----
    {
        const u32x4* esrc = ws_ekb + (size_t)(b * HH + h) * (4 * SS);
        #pragma unroll
        for (int t = 0; t < 8; t++)
            sek[tid + t * 256] = esrc[tid + t * 256];
    }

    // eq for the wave's 2 rows -> SGPRs (wave-uniform); v2 = -2*v.
    float eq0[EE], eq1[EE], v2s[EE];
    {
        const float* q0 = ws_eqf + (((size_t)b * LL + lw) * HH + h) * EE;
        const float* q1 = q0 + HH * EE;
        #pragma unroll
        for (int e = 0; e < EE; e += 4) {
            float4 t0 = *(const float4*)(q0 + e);
            float4 t1 = *(const float4*)(q1 + e);
            eq0[e] = bcastf(t0.x); eq0[e+1] = bcastf(t0.y);
            eq0[e+2] = bcastf(t0.z); eq0[e+3] = bcastf(t0.w);
            eq1[e] = bcastf(t1.x); eq1[e+1] = bcastf(t1.y);
            eq1[e+2] = bcastf(t1.z); eq1[e+3] = bcastf(t1.w);
        }
        const float4* vr = (const float4*)vvec;
        #pragma unroll
        for (int e4 = 0; e4 < EE / 4; e4++) {
            float4 t = vr[e4];
            v2s[e4*4]   = -2.f * t.x; v2s[e4*4+1] = -2.f * t.y;
            v2s[e4*4+2] = -2.f * t.z; v2s[e4*4+3] = -2.f * t.w;
        }
    }
    __syncthreads();   // barrier 1: ek staged

    // ---- Phase 1: scores from LDS-resident ek. ----
    // Read: 4 ds_read_b128/iter (consecutive lanes -> consecutive 16B
    // entries = conflict-free); ~96 cyc VALU per read hides ds latency.
    float sc[2][SS / 64];
    for (int i = 0; i < SS / 64; i++) {
        const int s = lane + i * 64;
        u32x4 g0 = sek[s];
        u32x4 g1 = sek[SS + s];
        u32x4 g2 = sek[2 * SS + s];
        u32x4 g3 = sek[3 * SS + s];
        float a0[4] = {0.f, 0.f, 0.f, 0.f};
        float a1[4] = {0.f, 0.f, 0.f, 0.f};
        #define ELEM(E, F)                                                    \
        {                                                                     \
            float p0 = __builtin_fmaf(eq0[E], F, 1.f);                        \
            float p1 = __builtin_fmaf(eq1[E], F, 1.f);                        \
            a0[(E) & 3] = __builtin_fmaf(v2s[E], fast_rcp(p0), a0[(E) & 3]);  \
            a1[(E) & 3] = __builtin_fmaf(v2s[E], fast_rcp(p1), a1[(E) & 3]);  \
        }
        #define PAIR(u, E)                                                    \
        {                                                                     \
            float flo = __uint_as_float((u) << 16);                           \
            float fhi = __uint_as_float((u) & 0xffff0000u);                   \
            ELEM(E, flo) ELEM((E) + 1, fhi)                                   \
        }
        #define GRP(g, base)                                                  \
        {                                                                     \
            PAIR(g[0], (base) + 0) PAIR(g[1], (base) + 2)                     \
            PAIR(g[2], (base) + 4) PAIR(g[3], (base) + 6)                     \
        }
        GRP(g0, 0) GRP(g1, 8) GRP(g2, 16) GRP(g3, 24)
        #undef GRP
        #undef PAIR
        #undef ELEM
        sc[0][i] = (a0[0] + a0[1]) + (a0[2] + a0[3]);
        sc[1][i] = (a1[0] + a1[1]) + (a1[2] + a1[3]);
    }

    // ---- Phase 2: masks + per-row softmax -> sAb (bf16, chunk-swizzled) --
    {
        const float* kl = klen + (size_t)b * SS;
        float klv[SS / 64];
        #pragma unroll
        for (int i = 0; i < SS / 64; i++) klv[i] = kl[lane + i * 64];

        #pragma unroll
        for (int r = 0; r < 2; r++) {
            const float* mrow = mask + (size_t)(lw + r) * SS;
            float mx = -1e30f;
            #pragma unroll
            for (int i = 0; i < SS / 64; i++) {
                sc[r][i] += mrow[lane + i * 64] + klv[i];
                mx = fmaxf(mx, sc[r][i]);
            }
            #pragma unroll
            for (int off = 1; off < 64; off <<= 1) mx = fmaxf(mx, __shfl_xor(mx, off, 64));
            float ssum = 0.f;
            #pragma unroll
            for (int i = 0; i < SS / 64; i++) {
                sc[r][i] = __expf(sc[r][i] - mx);
                ssum += sc[r][i];
            }
            #pragma unroll
            for (int off = 1; off < 64; off <<= 1) ssum += __shfl_xor(ssum, off, 64);
            float inv = fast_rcp(ssum);
            const int row = 2 * w + r;
            const int fsw = (row * 5) & 7;     // chunk swizzle (verified 0-conflict)
            #pragma unroll
            for (int i = 0; i < SS / 64; i++) {
                int col = lane + i * 64;
                int pos = (((col >> 3) ^ fsw) << 3) | (col & 7);
                sAb[row][pos] = f2bf(sc[r][i] * inv);
            }
        }
    }
    __syncthreads();   // barrier 2: sAb handoff

    // ---- Phase 3: PV via MFMA; B-frag = 1 coalesced bf16x8 (frag image). --
    const int am  = lane & 15;
    const int qd  = lane >> 4;
    const int dof = w * 16 + am;
    const int fam = (am * 5) & 7;              // A-row swizzle (matches write)
    const bf16x8* vf =
        ws_vtf + ((size_t)((b * HH + h) * 4 + w) * 16) * 64 + lane;
    f32x4 acc = {0.f, 0.f, 0.f, 0.f};
    bf16x8 bcur = vf[0];
    for (int c = 0; c < SS / 32; c++) {
        bf16x8 bnxt = bcur;
        if (c < SS / 32 - 1) bnxt = vf[(c + 1) * 64];
        bf16x8 af = {0, 0, 0, 0, 0, 0, 0, 0};
        if (am < 8)
            af = *(const bf16x8*)&sAb[am][((c * 4 + qd) ^ fam) << 3];
        acc = __builtin_amdgcn_mfma_f32_16x16x32_bf16(af, bcur, acc, 0, 0, 0);
        bcur = bnxt;
    }
    // C layout: col = lane&15 (d), row = qd*4 + reg; valid rows 0..7 -> qd<2
    if (qd < 2) {
        float* orow = out + (((size_t)b * LL + l0 + qd * 4) * HH + h) * DD + dof;
        #pragma unroll
        for (int r = 0; r < 4; r++)
            orow[(size_t)r * (HH * DD)] = acc[r];
    }
}

extern "C" void kernel_launch(void* const* d_in, const int* in_sizes, int n_in,
                              void* d_out, int out_size, void* d_ws, size_t ws_size,
                              hipStream_t stream) {
    const float* q    = (const float*)d_in[0];
    const float* k    = (const float*)d_in[1];
    const float* vals = (const float*)d_in[2];
    const float* vvec = (const float*)d_in[3];
    const float* mask = (const float*)d_in[4];
    const float* klen = (const float*)d_in[5];
    float* outp = (float*)d_out;

    float* ws = (float*)d_ws;
    prep_kernel<<<dim3(640), dim3(256), 0, stream>>>(q, k, vals, ws);

    const u32x4* ws_ekb = (const u32x4*)((char*)d_ws + WS_EK_OFF);
    const float* ws_eqf = (const float*)((char*)d_ws + WS_EQ_OFF);
    const bf16x8* ws_vtf = (const bf16x8*)((char*)d_ws + WS_VT_OFF);
    addattn_kernel<<<dim3(BB * HH * (LL / 8)), dim3(256), 0, stream>>>(
        ws_ekb, ws_eqf, ws_vtf, vvec, mask, klen, outp);
}